// Round 9
// baseline (288.094 us; speedup 1.0000x reference)
//
#include <hip/hip_runtime.h>
#include <hip/hip_bf16.h>

typedef __attribute__((ext_vector_type(4))) float v4f;
typedef __attribute__((ext_vector_type(8))) short v8s;
typedef __attribute__((ext_vector_type(4))) unsigned v4u;
typedef __attribute__((ext_vector_type(2))) unsigned v2u;

// full RNE fp32->bf16
__device__ __forceinline__ short f2bf(float f) {
  union { float f; unsigned u; } v; v.f = f;
  unsigned r = v.u + 0x7FFFu + ((v.u >> 16) & 1u);
  return (short)(r >> 16);
}
// packed 2xfp32 -> bf16x2, single v_cvt_pk_bf16_f32
__device__ __forceinline__ unsigned pk2(float a, float b) {
  union { __hip_bfloat162 h; unsigned u; } c;
  c.h = __float22bfloat162_rn(make_float2(a, b));
  return c.u;
}

#define LDX_S 136   // 128 + 8 pad shorts
#define LDH_S 264   // 256 + 8 pad shorts
#define LDP_S 36    // 32 + 4 pad floats
#define XBUF (64 * LDX_S)   // 8704 shorts / buffer
#define HBUF (64 * LDH_S)   // 16896 shorts / buffer
#define PBUF (64 * LDP_S)   // 2304 floats / buffer
#define SMEM_BYTES (2*XBUF*2 + 2*HBUF*2 + 2*PBUF*4)   // 120832

// Single-launch, single-barrier 3-deep pipelined fused MLP (R8 structure).
// 512 threads = 8 waves; wave w owns hidden rows [w*32, w*32+32) — 96
// resident weight VGPRs, the proven allocator-feasible split. New in R9:
// weight fragments are built in-kernel from fp32 W1/W2 (no pack kernel, no
// second launch), and the stage-R reduce is spread over all 8 waves.
__global__ __launch_bounds__(512, 2) void mlp_v9(
    const float* __restrict__ xu, const float* __restrict__ xm,
    const void* __restrict__ eidx,
    const float* __restrict__ W1, const float* __restrict__ W2,
    const float* __restrict__ b1, const float* __restrict__ b2,
    const float* __restrict__ W3, const float* __restrict__ b3,
    float* __restrict__ out, int E)
{
  extern __shared__ __align__(16) char smem[];
  short* ldsX = (short*)smem;                       // [2][XBUF]
  short* ldsH = (short*)(smem + 2 * XBUF * 2);      // [2][HBUF]
  float* ldsP = (float*)(smem + 2 * XBUF * 2 + 2 * HBUF * 2); // [2][PBUF]

  const int t    = threadIdx.x;
  const int w    = t >> 6;        // wave 0..7 : hidden slice w*32
  const int lane = t & 63;
  const int quad = lane >> 4;
  const int lp   = lane & 15;

  // ---- build resident weight fragments in-kernel (A-operand layout for the
  // transposed product W^T as A: lane holds A'[n][k], n=mt*16+lp,
  // k=kt*32+quad*8+j). 192 strided dword loads/lane, L2/L3-broadcast.
  v8s rW1[2][4], rW2[2][8];
#pragma unroll
  for (int mi = 0; mi < 2; ++mi) {
    const int n = (w * 2 + mi) * 16 + lp;
#pragma unroll
    for (int kt = 0; kt < 4; ++kt) {
      const int k0 = kt * 32 + quad * 8;
      v8s f;
#pragma unroll
      for (int j = 0; j < 8; ++j) f[j] = f2bf(W1[(k0 + j) * 256 + n]);
      rW1[mi][kt] = f;
    }
  }
#pragma unroll
  for (int mi = 0; mi < 2; ++mi) {
    const int n = (w * 2 + mi) * 16 + lp;
#pragma unroll
    for (int kt = 0; kt < 8; ++kt) {
      const int k0 = kt * 32 + quad * 8;
      v8s f;
#pragma unroll
      for (int j = 0; j < 8; ++j) f[j] = f2bf(W2[(k0 + j) * 256 + n]);
      rW2[mi][kt] = f;
    }
  }

  // ---- resident bias / W3 fragments
  v4f rb1[2], rb2[2], rw3[2];
#pragma unroll
  for (int mi = 0; mi < 2; ++mi) {
    int nh0 = w * 32 + mi * 16 + quad * 4;
    rb1[mi] = *(const v4f*)(b1 + nh0);
    rb2[mi] = *(const v4f*)(b2 + nh0);
    rw3[mi] = *(const v4f*)(W3 + nh0);
  }
  const float bias3 = b3[0];

  // ---- index dtype detection: int64 iff odd 32-bit words are all zero
  const unsigned* ew = (const unsigned*)eidx;
  unsigned oddw = (lane < 32) ? ew[2 * lane + 1] : 0u;
  const bool i64 = (__ballot(oddw != 0u) == 0ull);

  const int gi = t >> 3, gq = t & 7;   // gather: 8 threads/edge, 8 feats/side
  const int ntiles = (E + 63) >> 6;
  const int S   = (int)gridDim.x;
  const int bid = (int)blockIdx.x;
  const int Tb  = (ntiles - bid + S - 1) / S;   // tiles this block owns (>=1)

  auto loadIdx = [&](int tl, int& row, int& col) {
    int gE = tl * 64 + gi;
    if (gE >= E || gE < 0) gE = 0;
    if (i64) {
      const long long* p = (const long long*)eidx;
      row = (int)p[gE]; col = (int)p[(long long)E + gE];
    } else {
      const int* p = (const int*)eidx;
      row = p[gE]; col = p[E + gE];
    }
  };

  v4f U0, U1, M0, M1;
  auto issueUM = [&](int row, int col) {
    const v4f* pu = (const v4f*)(xu + (size_t)row * 64 + gq * 8);
    const v4f* pm = (const v4f*)(xm + (size_t)col * 64 + gq * 8);
    U0 = pu[0]; U1 = pu[1]; M0 = pm[0]; M1 = pm[1];
  };

  // prologue: idx(t0) -> feats(t0) -> idx(t1)
  int rowN, colN;
  loadIdx(bid, rowN, colN);
  issueUM(rowN, colN);
  loadIdx(bid + S, rowN, colN);

  // stage-R roles: 8 threads per edge, each reduces one v4f slot
  const int re = t >> 3, rs = t & 7;

  for (int k = 0; k <= Tb + 2; ++k) {
    __syncthreads();                 // publishes ALL of phase k-1's LDS writes
    const int pb = k & 1;
    const int tg = bid + k * S;      // tile being gather-committed this phase

    // ---- stage G: commit prefetched features -> ldsX[pb]
    if (k < Tb) {
      short* px = &ldsX[pb * XBUF + gi * LDX_S + gq * 8];
      v4u a = { pk2(U0[0], U0[1]), pk2(U0[2], U0[3]),
                pk2(U1[0], U1[1]), pk2(U1[2], U1[3]) };
      v4u c = { pk2(M0[0], M0[1]), pk2(M0[2], M0[3]),
                pk2(M1[0], M1[1]), pk2(M1[2], M1[3]) };
      *(v4u*)(px)      = a;     // user  -> k 0..63
      *(v4u*)(px + 64) = c;     // movie -> k 64..127
    }
    // ---- prefetch: features(t_{k+1}), indices(t_{k+2})
    if (k + 1 < Tb) {
      issueUM(rowN, colN);
      loadIdx(tg + 2 * S, rowN, colN);
    }

    // ---- stage R: reduce + store tile t3 = tg - 3S from ldsP[pb^1]
    //      distributed: 8 threads/edge, one v4f each, shfl_xor tree
    const int t3 = tg - 3 * S;
    if (t3 >= 0) {
      v4f p = *(const v4f*)&ldsP[(pb ^ 1) * PBUF + re * LDP_S + rs * 4];
      float r = (p[0] + p[1]) + (p[2] + p[3]);
      r += __shfl_xor(r, 1);
      r += __shfl_xor(r, 2);
      r += __shfl_xor(r, 4);
      int o = t3 * 64 + re;
      if (rs == 0 && o < E) out[o] = r + bias3;
    }

    // ---- stage L1: layer 1 of t1 = tg - S : ldsX[pb^1] -> ldsH[pb^1]
    const int t1 = tg - S;
    if (t1 >= 0 && t1 < ntiles) {
      v4f acc[2][4];
#pragma unroll
      for (int mi = 0; mi < 2; ++mi)
#pragma unroll
        for (int ni = 0; ni < 4; ++ni)
          acc[mi][ni] = rb1[mi];
#pragma unroll
      for (int kt = 0; kt < 4; ++kt) {
        v8s b[4];
#pragma unroll
        for (int ni = 0; ni < 4; ++ni)
          b[ni] = *(const v8s*)&ldsX[(pb ^ 1) * XBUF + (ni * 16 + lp) * LDX_S + kt * 32 + quad * 8];
#pragma unroll
        for (int mi = 0; mi < 2; ++mi)
#pragma unroll
          for (int ni = 0; ni < 4; ++ni)
            acc[mi][ni] = __builtin_amdgcn_mfma_f32_16x16x32_bf16(rW1[mi][kt], b[ni], acc[mi][ni], 0, 0, 0);
      }
#pragma unroll
      for (int mi = 0; mi < 2; ++mi) {
        int nh0 = w * 32 + mi * 16 + quad * 4;
#pragma unroll
        for (int ni = 0; ni < 4; ++ni) {
          int e = ni * 16 + lp;
          v4f v = acc[mi][ni];
          v2u pw; pw.x = pk2(fmaxf(v[0], 0.f), fmaxf(v[1], 0.f));
          pw.y = pk2(fmaxf(v[2], 0.f), fmaxf(v[3], 0.f));
          *(v2u*)&ldsH[(pb ^ 1) * HBUF + e * LDH_S + nh0] = pw;   // ds_write_b64
        }
      }
    }

    // ---- stage L2: layer 2+3 of t2 = tg - 2S : ldsH[pb] -> ldsP[pb]
    const int t2 = tg - 2 * S;
    if (t2 >= 0 && t2 < ntiles) {
      v4f acc2[2][4];
#pragma unroll
      for (int mi = 0; mi < 2; ++mi)
#pragma unroll
        for (int ni = 0; ni < 4; ++ni)
          acc2[mi][ni] = rb2[mi];
#pragma unroll
      for (int kt = 0; kt < 8; ++kt) {
        v8s b[4];
#pragma unroll
        for (int ni = 0; ni < 4; ++ni)
          b[ni] = *(const v8s*)&ldsH[pb * HBUF + (ni * 16 + lp) * LDH_S + kt * 32 + quad * 8];
#pragma unroll
        for (int mi = 0; mi < 2; ++mi)
#pragma unroll
          for (int ni = 0; ni < 4; ++ni)
            acc2[mi][ni] = __builtin_amdgcn_mfma_f32_16x16x32_bf16(rW2[mi][kt], b[ni], acc2[mi][ni], 0, 0, 0);
      }
      float s[4] = {0.f, 0.f, 0.f, 0.f};
#pragma unroll
      for (int mi = 0; mi < 2; ++mi) {
#pragma unroll
        for (int ni = 0; ni < 4; ++ni) {
          v4f v = acc2[mi][ni];
#pragma unroll
          for (int r = 0; r < 4; ++r)
            s[ni] += fmaxf(v[r], 0.f) * rw3[mi][r];
        }
      }
#pragma unroll
      for (int ni = 0; ni < 4; ++ni)
        ldsP[pb * PBUF + (ni * 16 + lp) * LDP_S + w * 4 + quad] = s[ni];
    }
  }
}

extern "C" void kernel_launch(void* const* d_in, const int* in_sizes, int n_in,
                              void* d_out, int out_size, void* d_ws, size_t ws_size,
                              hipStream_t stream) {
  const float* xu  = (const float*)d_in[0];
  const float* xm  = (const float*)d_in[1];
  const void*  ei  = d_in[2];
  const float* W1  = (const float*)d_in[3];
  const float* b1  = (const float*)d_in[4];
  const float* W2  = (const float*)d_in[5];
  const float* b2  = (const float*)d_in[6];
  const float* W3  = (const float*)d_in[7];
  const float* b3  = (const float*)d_in[8];
  float* out = (float*)d_out;

  const int E = in_sizes[2] / 2;

  // 118 KB dynamic LDS (> 64 KB static limit); idempotent, graph-capture-safe
  hipFuncSetAttribute((const void*)mlp_v9,
                      hipFuncAttributeMaxDynamicSharedMemorySize, SMEM_BYTES);

  const int ntiles = (E + 63) / 64;
  const int nblk = ntiles < 256 ? ntiles : 256;
  hipLaunchKernelGGL(mlp_v9, dim3(nblk), dim3(512), SMEM_BYTES, stream,
                     xu, xm, ei, W1, W2, b1, b2, W3, b3, out, E);
}

// Round 10
// 275.260 us; speedup vs baseline: 1.0466x; 1.0466x over previous
//
#include <hip/hip_runtime.h>
#include <hip/hip_bf16.h>

typedef __attribute__((ext_vector_type(4))) float v4f;
typedef __attribute__((ext_vector_type(8))) short v8s;
typedef __attribute__((ext_vector_type(4))) unsigned v4u;
typedef __attribute__((ext_vector_type(2))) unsigned v2u;

// full RNE fp32->bf16 (prep kernel only)
__device__ __forceinline__ short f2bf(float f) {
  union { float f; unsigned u; } v; v.f = f;
  unsigned r = v.u + 0x7FFFu + ((v.u >> 16) & 1u);
  return (short)(r >> 16);
}
// packed 2xfp32 -> bf16x2, single v_cvt_pk_bf16_f32
__device__ __forceinline__ unsigned pk2(float a, float b) {
  union { __hip_bfloat162 h; unsigned u; } c;
  c.h = __float22bfloat162_rn(make_float2(a, b));
  return c.u;
}

// Pack W1 [128x256] and W2 [256x256] (row-major [k][n], fp32) into bf16 MFMA
// A-operand fragment order for the transposed product (W^T as A):
//   lane l of fragment (mt, kt) holds A'[n = mt*16 + (l&15)][k = kt*32 + (l>>4)*8 + j]
// W2's k-index is PERMUTED to match the physical H layout the main kernel
// writes (physical p = 32*kt + 8*q + 4*mi + r holds logical n1 = 32*kt +
// 16*mi + 4*q + r), so layer-2 reads B by physical slot and A supplies the
// matching logical W2 row: k_logical = kt*32 + (j>>2)*16 + quad*4 + (j&3).
__global__ void pack_weights(const float* __restrict__ W1, const float* __restrict__ W2,
                             short* __restrict__ pW1, short* __restrict__ pW2) {
  int tid = blockIdx.x * 256 + threadIdx.x;
  if (tid < 32768) {
    int j = tid & 7, l = (tid >> 3) & 63, frag = tid >> 9;
    int mt = frag >> 2, kt = frag & 3;
    int n = mt * 16 + (l & 15);
    int k = kt * 32 + ((l >> 4) * 8) + j;
    pW1[tid] = f2bf(W1[k * 256 + n]);
  } else if (tid < 98304) {
    int t2 = tid - 32768;
    int j = t2 & 7, l = (t2 >> 3) & 63, frag = t2 >> 9;
    int mt = frag >> 3, kt = frag & 7;
    int n = mt * 16 + (l & 15);
    int q = (l >> 4) & 3;
    int kl = kt * 32 + ((j >> 2) * 16) + q * 4 + (j & 3);   // permuted k
    pW2[t2] = f2bf(W2[kl * 256 + n]);
  }
}

#define LDX_S 136   // 128 + 8 pad shorts
#define LDH_S 264   // 256 + 8 pad shorts
#define LDP_S 36    // 32 + 4 pad floats
#define XBUF (64 * LDX_S)   // 8704 shorts / buffer
#define HBUF (64 * LDH_S)   // 16896 shorts / buffer
#define PBUF (64 * LDP_S)   // 2304 floats / buffer
#define SMEM_BYTES (2*XBUF*2 + 2*HBUF*2 + 2*PBUF*4)   // 120832

// Single-barrier 3-deep pipelined fused MLP (R8 structure, best measured).
// 512 threads = 8 waves; wave w owns hidden rows [w*32, w*32+32) — 96
// resident weight VGPRs (the allocator-feasible split). R10: H epilogue
// writes 4x ds_write_b128 (permuted physical layout) instead of 8x b64;
// stage-R reduce distributed over all 8 waves.
__global__ __launch_bounds__(512, 2) void mlp_v10(
    const float* __restrict__ xu, const float* __restrict__ xm,
    const void* __restrict__ eidx,
    const short* __restrict__ pW1, const short* __restrict__ pW2,
    const float* __restrict__ b1, const float* __restrict__ b2,
    const float* __restrict__ W3, const float* __restrict__ b3,
    float* __restrict__ out, int E)
{
  extern __shared__ __align__(16) char smem[];
  short* ldsX = (short*)smem;                       // [2][XBUF]
  short* ldsH = (short*)(smem + 2 * XBUF * 2);      // [2][HBUF]
  float* ldsP = (float*)(smem + 2 * XBUF * 2 + 2 * HBUF * 2); // [2][PBUF]

  const int t    = threadIdx.x;
  const int w    = t >> 6;        // wave 0..7 : hidden slice w*32
  const int lane = t & 63;
  const int quad = lane >> 4;
  const int lp   = lane & 15;

  // ---- resident weight fragments (96 VGPRs/wave, loaded once)
  const v8s* w1v = (const v8s*)pW1;
  const v8s* w2v = (const v8s*)pW2;
  v8s rW1[2][4], rW2[2][8];
#pragma unroll
  for (int mi = 0; mi < 2; ++mi)
#pragma unroll
    for (int kt = 0; kt < 4; ++kt)
      rW1[mi][kt] = w1v[(((w * 2 + mi) * 4) + kt) * 64 + lane];
#pragma unroll
  for (int mi = 0; mi < 2; ++mi)
#pragma unroll
    for (int kt = 0; kt < 8; ++kt)
      rW2[mi][kt] = w2v[(((w * 2 + mi) * 8) + kt) * 64 + lane];

  // ---- resident bias / W3 fragments (logical n = w*32 + mi*16 + quad*4 + r)
  v4f rb1[2], rb2[2], rw3[2];
#pragma unroll
  for (int mi = 0; mi < 2; ++mi) {
    int nh0 = w * 32 + mi * 16 + quad * 4;
    rb1[mi] = *(const v4f*)(b1 + nh0);
    rb2[mi] = *(const v4f*)(b2 + nh0);
    rw3[mi] = *(const v4f*)(W3 + nh0);
  }
  const float bias3 = b3[0];

  // ---- index dtype detection: int64 iff odd 32-bit words are all zero
  const unsigned* ew = (const unsigned*)eidx;
  unsigned oddw = (lane < 32) ? ew[2 * lane + 1] : 0u;
  const bool i64 = (__ballot(oddw != 0u) == 0ull);

  const int gi = t >> 3, gq = t & 7;   // gather: 8 threads/edge, 8 feats/side
  const int ntiles = (E + 63) >> 6;
  const int S   = (int)gridDim.x;
  const int bid = (int)blockIdx.x;
  const int Tb  = (ntiles - bid + S - 1) / S;   // tiles this block owns (>=1)

  auto loadIdx = [&](int tl, int& row, int& col) {
    int gE = tl * 64 + gi;
    if (gE >= E || gE < 0) gE = 0;
    if (i64) {
      const long long* p = (const long long*)eidx;
      row = (int)p[gE]; col = (int)p[(long long)E + gE];
    } else {
      const int* p = (const int*)eidx;
      row = p[gE]; col = p[E + gE];
    }
  };

  v4f U0, U1, M0, M1;
  auto issueUM = [&](int row, int col) {
    const v4f* pu = (const v4f*)(xu + (size_t)row * 64 + gq * 8);
    const v4f* pm = (const v4f*)(xm + (size_t)col * 64 + gq * 8);
    U0 = pu[0]; U1 = pu[1]; M0 = pm[0]; M1 = pm[1];
  };

  // prologue: idx(t0) -> feats(t0) -> idx(t1)
  int rowN, colN;
  loadIdx(bid, rowN, colN);
  issueUM(rowN, colN);
  loadIdx(bid + S, rowN, colN);

  // stage-R roles: 8 threads per edge, each reduces one v4f slot
  const int re = t >> 3, rs = t & 7;

  for (int k = 0; k <= Tb + 2; ++k) {
    __syncthreads();                 // publishes ALL of phase k-1's LDS writes
    const int pb = k & 1;
    const int tg = bid + k * S;      // tile being gather-committed this phase

    // ---- stage G: commit prefetched features -> ldsX[pb]
    if (k < Tb) {
      short* px = &ldsX[pb * XBUF + gi * LDX_S + gq * 8];
      v4u a = { pk2(U0[0], U0[1]), pk2(U0[2], U0[3]),
                pk2(U1[0], U1[1]), pk2(U1[2], U1[3]) };
      v4u c = { pk2(M0[0], M0[1]), pk2(M0[2], M0[3]),
                pk2(M1[0], M1[1]), pk2(M1[2], M1[3]) };
      *(v4u*)(px)      = a;     // user  -> k 0..63
      *(v4u*)(px + 64) = c;     // movie -> k 64..127
    }
    // ---- prefetch: features(t_{k+1}), indices(t_{k+2})
    if (k + 1 < Tb) {
      issueUM(rowN, colN);
      loadIdx(tg + 2 * S, rowN, colN);
    }

    // ---- stage R: reduce + store tile t3 = tg - 3S from ldsP[pb^1]
    //      distributed: 8 threads/edge, one v4f each, shfl_xor tree
    const int t3 = tg - 3 * S;
    if (t3 >= 0) {
      v4f p = *(const v4f*)&ldsP[(pb ^ 1) * PBUF + re * LDP_S + rs * 4];
      float r = (p[0] + p[1]) + (p[2] + p[3]);
      r += __shfl_xor(r, 1);
      r += __shfl_xor(r, 2);
      r += __shfl_xor(r, 4);
      int o = t3 * 64 + re;
      if (rs == 0 && o < E) out[o] = r + bias3;
    }

    // ---- stage L1: layer 1 of t1 = tg - S : ldsX[pb^1] -> ldsH[pb^1]
    const int t1 = tg - S;
    if (t1 >= 0 && t1 < ntiles) {
      v4f acc[2][4];
#pragma unroll
      for (int mi = 0; mi < 2; ++mi)
#pragma unroll
        for (int ni = 0; ni < 4; ++ni)
          acc[mi][ni] = rb1[mi];
#pragma unroll
      for (int kt = 0; kt < 4; ++kt) {
        v8s b[4];
#pragma unroll
        for (int ni = 0; ni < 4; ++ni)
          b[ni] = *(const v8s*)&ldsX[(pb ^ 1) * XBUF + (ni * 16 + lp) * LDX_S + kt * 32 + quad * 8];
#pragma unroll
        for (int mi = 0; mi < 2; ++mi)
#pragma unroll
          for (int ni = 0; ni < 4; ++ni)
            acc[mi][ni] = __builtin_amdgcn_mfma_f32_16x16x32_bf16(rW1[mi][kt], b[ni], acc[mi][ni], 0, 0, 0);
      }
      // epilogue 1: relu + pack; physical slot p = w*32 + quad*8 + mi*4 + r
      // (holds logical n = w*32 + mi*16 + quad*4 + r; W2 pack compensates)
      // -> one ds_write_b128 of 8 consecutive shorts per (ni)
#pragma unroll
      for (int ni = 0; ni < 4; ++ni) {
        int e = ni * 16 + lp;
        v4f v0 = acc[0][ni];
        v4f v1 = acc[1][ni];
        v4u pw = { pk2(fmaxf(v0[0], 0.f), fmaxf(v0[1], 0.f)),
                   pk2(fmaxf(v0[2], 0.f), fmaxf(v0[3], 0.f)),
                   pk2(fmaxf(v1[0], 0.f), fmaxf(v1[1], 0.f)),
                   pk2(fmaxf(v1[2], 0.f), fmaxf(v1[3], 0.f)) };
        *(v4u*)&ldsH[(pb ^ 1) * HBUF + e * LDH_S + w * 32 + quad * 8] = pw;
      }
    }

    // ---- stage L2: layer 2+3 of t2 = tg - 2S : ldsH[pb] -> ldsP[pb]
    const int t2 = tg - 2 * S;
    if (t2 >= 0 && t2 < ntiles) {
      v4f acc2[2][4];
#pragma unroll
      for (int mi = 0; mi < 2; ++mi)
#pragma unroll
        for (int ni = 0; ni < 4; ++ni)
          acc2[mi][ni] = rb2[mi];
#pragma unroll
      for (int kt = 0; kt < 8; ++kt) {
        v8s b[4];
#pragma unroll
        for (int ni = 0; ni < 4; ++ni)
          b[ni] = *(const v8s*)&ldsH[pb * HBUF + (ni * 16 + lp) * LDH_S + kt * 32 + quad * 8];
#pragma unroll
        for (int mi = 0; mi < 2; ++mi)
#pragma unroll
          for (int ni = 0; ni < 4; ++ni)
            acc2[mi][ni] = __builtin_amdgcn_mfma_f32_16x16x32_bf16(rW2[mi][kt], b[ni], acc2[mi][ni], 0, 0, 0);
      }
      float s[4] = {0.f, 0.f, 0.f, 0.f};
#pragma unroll
      for (int mi = 0; mi < 2; ++mi) {
#pragma unroll
        for (int ni = 0; ni < 4; ++ni) {
          v4f v = acc2[mi][ni];
#pragma unroll
          for (int r = 0; r < 4; ++r)
            s[ni] += fmaxf(v[r], 0.f) * rw3[mi][r];
        }
      }
#pragma unroll
      for (int ni = 0; ni < 4; ++ni)
        ldsP[pb * PBUF + (ni * 16 + lp) * LDP_S + w * 4 + quad] = s[ni];
    }
  }
}

extern "C" void kernel_launch(void* const* d_in, const int* in_sizes, int n_in,
                              void* d_out, int out_size, void* d_ws, size_t ws_size,
                              hipStream_t stream) {
  const float* xu  = (const float*)d_in[0];
  const float* xm  = (const float*)d_in[1];
  const void*  ei  = d_in[2];
  const float* W1  = (const float*)d_in[3];
  const float* b1  = (const float*)d_in[4];
  const float* W2  = (const float*)d_in[5];
  const float* b2  = (const float*)d_in[6];
  const float* W3  = (const float*)d_in[7];
  const float* b3  = (const float*)d_in[8];
  float* out = (float*)d_out;

  const int E = in_sizes[2] / 2;

  short* pW1 = (short*)d_ws;          // 64 KB
  short* pW2 = pW1 + 32768;           // 128 KB

  hipLaunchKernelGGL(pack_weights, dim3(384), dim3(256), 0, stream, W1, W2, pW1, pW2);

  // 118 KB dynamic LDS (> 64 KB static limit); idempotent, graph-capture-safe
  hipFuncSetAttribute((const void*)mlp_v10,
                      hipFuncAttributeMaxDynamicSharedMemorySize, SMEM_BYTES);

  const int ntiles = (E + 63) / 64;
  const int nblk = ntiles < 256 ? ntiles : 256;
  hipLaunchKernelGGL(mlp_v10, dim3(nblk), dim3(512), SMEM_BYTES, stream,
                     xu, xm, ei, pW1, pW2, b1, b2, W3, b3, out, E);
}